// Round 8
// baseline (280.204 us; speedup 1.0000x reference)
//
#include <hip/hip_runtime.h>

#define NTOK 4096
#define DIM 1024
#define NE 8
#define NPAIR (NTOK * 2)

typedef __bf16 bf16x8 __attribute__((ext_vector_type(8)));
typedef float floatx4 __attribute__((ext_vector_type(4)));

__device__ __forceinline__ unsigned short f2bf(float f) {
  unsigned u = __float_as_uint(f);
  u = u + 0x7fffu + ((u >> 16) & 1u);
  return (unsigned short)(u >> 16);
}
__device__ __forceinline__ float bf2f(unsigned short h) {
  return __uint_as_float(((unsigned)h) << 16);
}

__device__ __forceinline__ void gld_lds16(const unsigned short* g, unsigned short* l) {
  __builtin_amdgcn_global_load_lds(
      (const __attribute__((address_space(1))) void*)g,
      (__attribute__((address_space(3))) void*)l, 16, 0, 0);
}

// ---------------- gating: one WAVE per token; block 0 zeroes cnt/done ------------------
__global__ __launch_bounds__(256) void gate_kernel(
    const float* __restrict__ x, const float* __restrict__ gW,
    const float* __restrict__ gb,
    float* __restrict__ gp_out, int2* __restrict__ tops,
    float* __restrict__ pairw, int* __restrict__ cnt, int* __restrict__ done)
{
  const int tid = threadIdx.x;
  if (blockIdx.x == 0) {
    if (tid < NE) cnt[tid] = 0;
    if (tid == NE) *done = 0;
  }
  const int lane = tid & 63;
  const int wid = tid >> 6;
  const int t = blockIdx.x * 4 + wid;

  float4 xv[4];
#pragma unroll
  for (int j = 0; j < 4; j++)
    xv[j] = ((const float4*)(x + (size_t)t * DIM))[lane + 64 * j];

  float p[NE];
#pragma unroll
  for (int e = 0; e < NE; e++) {
    const float4* gwe = (const float4*)(gW + e * DIM);
    float s = 0.f;
#pragma unroll
    for (int j = 0; j < 4; j++) {
      float4 g = gwe[lane + 64 * j];
      s += xv[j].x * g.x + xv[j].y * g.y + xv[j].z * g.z + xv[j].w * g.w;
    }
    p[e] = s;
  }
#pragma unroll
  for (int e = 0; e < NE; e++) {
#pragma unroll
    for (int off = 32; off >= 1; off >>= 1) p[e] += __shfl_xor(p[e], off);
  }

  float m = -1e30f;
#pragma unroll
  for (int e = 0; e < NE; e++) { p[e] += gb[e]; m = fmaxf(m, p[e]); }
  float s = 0.f;
  float pr[NE];
#pragma unroll
  for (int e = 0; e < NE; e++) { pr[e] = __expf(p[e] - m); s += pr[e]; }
  float inv = 1.f / s;
#pragma unroll
  for (int e = 0; e < NE; e++) pr[e] *= inv;

  if (lane < NE) gp_out[(size_t)t * NE + lane] = pr[lane];

  if (lane == 0) {
    int i0 = 0;
#pragma unroll
    for (int e = 1; e < NE; e++) if (pr[e] > pr[i0]) i0 = e;
    int i1 = (i0 == 0) ? 1 : 0;
#pragma unroll
    for (int e = 0; e < NE; e++) if (e != i0 && pr[e] > pr[i1]) i1 = e;
    float d = __expf(pr[i1] - pr[i0]);
    float w0 = 1.f / (1.f + d);
    tops[t] = make_int2(i0, i1);
    pairw[t * 2] = w0;
    pairw[t * 2 + 1] = 1.f - w0;
  }
}

// ------- binning + schedule: wave-aggregated atomics; last block builds sched ----------
__global__ __launch_bounds__(256) void bin_sched_kernel(
    const int2* __restrict__ tops, int* __restrict__ cnt,
    int* __restrict__ bucket,      // [NE][NTOK]: pair id per within-expert index
    int* __restrict__ done, int* __restrict__ base,   // base[9]
    int* __restrict__ sched, int* __restrict__ sched_n)
{
  const int t = blockIdx.x * 256 + threadIdx.x;
  const int lane = threadIdx.x & 63;
  int2 ti = tops[t];
#pragma unroll
  for (int slot = 0; slot < 2; slot++) {
    int e = slot ? ti.y : ti.x;
#pragma unroll
    for (int ex = 0; ex < NE; ex++) {
      bool mine = (e == ex);
      unsigned long long mask = __ballot(mine);
      if (mask) {
        int leader = __ffsll((long long)mask) - 1;
        int total = __popcll(mask);
        int prefix = __popcll(mask & ((1ull << lane) - 1ull));
        int idx = 0;
        if (lane == leader) idx = atomicAdd(&cnt[ex], total);
        idx = __shfl(idx, leader) + prefix;
        if (mine) bucket[ex * NTOK + idx] = t * 2 + slot;
      }
    }
  }
  __syncthreads();
  if (threadIdx.x == 0) {
    if (atomicAdd(done, 1) == gridDim.x - 1) {   // last block: build schedule
      int b = 0, pos = 0;
      for (int e = 0; e < NE; e++) {
        int c = atomicAdd(&cnt[e], 0);           // device-coherent read
        base[e] = b;
        int tiles = (c + 127) >> 7;
        for (int i = 0; i < tiles; i++) {
          int valid = c - i * 128; if (valid > 128) valid = 128;
          sched[pos++] = (e << 20) | (i << 8) | valid;
        }
        b += c;
      }
      base[NE] = b;
      *sched_n = pos;
    }
  }
}

// ---------------- fp32 -> bf16 weight conversion (w2, after gemm1 frees region0) -------
__global__ __launch_bounds__(256) void cvt_kernel(
    const float4* __restrict__ src, ushort4* __restrict__ dst)
{
  const int i = blockIdx.x * 256 + threadIdx.x;
  float4 v = src[i];
  ushort4 o;
  o.x = f2bf(v.x); o.y = f2bf(v.y); o.z = f2bf(v.z); o.w = f2bf(v.w);
  dst[i] = o;
}

// -------- pack tokens (x fp32 -> bf16) + fused w1 conversion ---------------------------
__global__ __launch_bounds__(256) void gather_cvt_kernel(
    const float* __restrict__ x, const int* __restrict__ bucket,
    const int* __restrict__ base, unsigned short* __restrict__ A_pack,
    const float4* __restrict__ w1, ushort4* __restrict__ w1_bf)
{
  const int p = blockIdx.x;
  const int tid = threadIdx.x;

  {  // fused w1 cvt: 8192 blocks x 256 threads x 1 float4 = 32 MB
    const int i = p * 256 + tid;
    float4 v = w1[i];
    ushort4 o;
    o.x = f2bf(v.x); o.y = f2bf(v.y); o.z = f2bf(v.z); o.w = f2bf(v.w);
    w1_bf[i] = o;
  }

  int e = 0;
#pragma unroll
  for (int k = 0; k < NE - 1; k++) if (p >= base[k + 1]) e = k + 1;
  const int pair = bucket[e * NTOK + (p - base[e])];
  const int tok = pair >> 1;
  float4 v = ((const float4*)(x + (size_t)tok * DIM))[tid];
  ushort4 o;
  o.x = f2bf(v.x); o.y = f2bf(v.y); o.z = f2bf(v.z); o.w = f2bf(v.w);
  ((ushort4*)(A_pack + (size_t)p * DIM))[tid] = o;
}

// ---------------- split-K grouped GEMM: 128x128 tile, BK=64, K=512/half ----------------
// Grid 1152 = 8 n-tiles x 144 units (72 slots x 2 K-halves). unit = sh*8 + xcd:
// units round-robin XCDs; all 8 n-tiles of a unit on one XCD (A-slice L2 dup=1).
// Per-wave 64x64 sub-tile -> 32 FLOP per LDS byte (2x R7) -> LDS ceiling ~1.7 PF.
// MODE 0 (gemm1): plain-store bf16 partial to P_lo/P_hi (no bias/relu here).
// MODE 1 (gemm2): epilogue atomicAdd into y: w_pair * (partial + 0.5*b2).
template <int MODE>
__global__ __launch_bounds__(256) void ffn_gemm(
    const unsigned short* __restrict__ A,     // packed [NPAIR][DIM]
    const unsigned short* __restrict__ B,     // [NE][DIM][DIM]
    const float* __restrict__ bias,           // [NE][DIM] (MODE 1 only)
    const int* __restrict__ base,
    const int* __restrict__ sched, const int* __restrict__ sched_n,
    const int* __restrict__ bucket, const float* __restrict__ pairw,
    unsigned short* __restrict__ P_lo, unsigned short* __restrict__ P_hi,
    float* __restrict__ y)
{
  const int l = blockIdx.x;
  const int xcd = l & 7;
  const int j = l >> 3;
  const int nt = j & 7;                      // 8 n-tiles of 128 cols
  const int unit = (j >> 3) * 8 + xcd;       // 0..143, round-robin over XCDs
  const int slot = unit >> 1;
  const int half = unit & 1;
  if (slot >= *sched_n) return;
  const int se = sched[slot];
  const int e = se >> 20;
  const int mt = (se >> 8) & 0xfff;
  const int valid = se & 255;                // valid rows in this tile (1..128)
  const int arow0 = base[e] + mt * 128;
  const int kbase = half * 512;

  __shared__ unsigned short lda[128 * 64];   // 16 KB
  __shared__ unsigned short ldb[128 * 64];   // 16 KB (32 KB -> 5 blocks/CU cap)

  const int tid = threadIdx.x;
  const int lane = tid & 63;
  const int wid = tid >> 6;

  const unsigned short* ap[4];
  const unsigned short* bp[4];
#pragma unroll
  for (int j0 = 0; j0 < 4; j0++) {
    int row = wid * 32 + j0 * 8 + (lane >> 3);
    int gran = (lane & 7) ^ (row & 7);       // source-side XOR swizzle (0 conflicts)
    int prow = arow0 + row;                  // clamp pad rows in-bounds (store-masked)
    if (prow > NPAIR - 1) prow = NPAIR - 1;
    ap[j0] = A + (size_t)prow * DIM + kbase + (gran << 3);
    bp[j0] = B + ((size_t)e * DIM + nt * 128 + row) * DIM + kbase + (gran << 3);
  }

  floatx4 acc[4][4] = {};
  const int wm = (wid & 1) * 64;
  const int wn = (wid >> 1) * 64;
  const int quad = lane >> 4;
  const int cl = lane & 15;
  const int sw = cl & 7;

  for (int k0 = 0; k0 < 8; k0++) {
#pragma unroll
    for (int j0 = 0; j0 < 4; j0++) {
      int g = wid * 4 + j0;
      gld_lds16(ap[j0], &lda[g * 512]);
      gld_lds16(bp[j0], &ldb[g * 512]);
      ap[j0] += 64;
      bp[j0] += 64;
    }
    __syncthreads();
#pragma unroll
    for (int kk = 0; kk < 64; kk += 32) {
      const int gb = (kk >> 3) + quad;
      const int goff = ((gb ^ sw) << 3);
      bf16x8 af[4], bfr[4];
#pragma unroll
      for (int mi = 0; mi < 4; mi++)
        af[mi] = *(const bf16x8*)&lda[(wm + mi * 16 + cl) * 64 + goff];
#pragma unroll
      for (int ni = 0; ni < 4; ni++)
        bfr[ni] = *(const bf16x8*)&ldb[(wn + ni * 16 + cl) * 64 + goff];
#pragma unroll
      for (int mi = 0; mi < 4; mi++)
#pragma unroll
        for (int ni = 0; ni < 4; ni++)
          acc[mi][ni] = __builtin_amdgcn_mfma_f32_16x16x32_bf16(af[mi], bfr[ni], acc[mi][ni], 0, 0, 0);
    }
    if (k0 < 7) __syncthreads();
  }

  // epilogue: C/D layout col=lane&15, row=(lane>>4)*4+reg [m89-verified]
  if (MODE == 0) {
    unsigned short* P = half ? P_hi : P_lo;
#pragma unroll
    for (int ni = 0; ni < 4; ni++) {
      int col = nt * 128 + wn + ni * 16 + cl;
#pragma unroll
      for (int mi = 0; mi < 4; mi++) {
#pragma unroll
        for (int reg = 0; reg < 4; reg++) {
          int rl = wm + mi * 16 + quad * 4 + reg;
          if (rl < valid)
            P[(size_t)(arow0 + rl) * DIM + col] = f2bf(acc[mi][ni][reg]);
        }
      }
    }
  } else {
    // per-row pair weight + token (16 rows/thread, reused across 4 ni)
    float wrow[16];
    int trow[16];
#pragma unroll
    for (int mi = 0; mi < 4; mi++) {
#pragma unroll
      for (int reg = 0; reg < 4; reg++) {
        int rl = wm + mi * 16 + quad * 4 + reg;
        if (rl < valid) {
          int pair = bucket[e * NTOK + mt * 128 + rl];
          wrow[mi * 4 + reg] = pairw[pair];
          trow[mi * 4 + reg] = pair >> 1;
        }
      }
    }
#pragma unroll
    for (int ni = 0; ni < 4; ni++) {
      int col = nt * 128 + wn + ni * 16 + cl;
      float bh = 0.5f * bias[e * DIM + col];   // each K-half adds half the bias
#pragma unroll
      for (int mi = 0; mi < 4; mi++) {
#pragma unroll
        for (int reg = 0; reg < 4; reg++) {
          int rl = wm + mi * 16 + quad * 4 + reg;
          if (rl < valid)
            atomicAdd(&y[(size_t)trow[mi * 4 + reg] * DIM + col],
                      wrow[mi * 4 + reg] * (acc[mi][ni][reg] + bh));
        }
      }
    }
  }
}

// ---------------- reduce1: h = relu(P_lo + P_hi + b1), in-place over P_lo --------------
__global__ __launch_bounds__(256) void reduce1_kernel(
    unsigned short* __restrict__ P_lo, const unsigned short* __restrict__ P_hi,
    const float* __restrict__ b1, const int* __restrict__ base)
{
  const int i = blockIdx.x * 256 + threadIdx.x;   // ushort4 index
  const int p = i >> 8;                           // packed row (DIM/4 = 256 per row)
  int e = 0;
#pragma unroll
  for (int k = 0; k < NE - 1; k++) if (p >= base[k + 1]) e = k + 1;
  ushort4 a = ((const ushort4*)P_lo)[i];
  ushort4 b = ((const ushort4*)P_hi)[i];
  float4 bb = ((const float4*)(b1 + e * DIM))[i & 255];
  ushort4 o;
  o.x = f2bf(fmaxf(bf2f(a.x) + bf2f(b.x) + bb.x, 0.f));
  o.y = f2bf(fmaxf(bf2f(a.y) + bf2f(b.y) + bb.y, 0.f));
  o.z = f2bf(fmaxf(bf2f(a.z) + bf2f(b.z) + bb.z, 0.f));
  o.w = f2bf(fmaxf(bf2f(a.w) + bf2f(b.w) + bb.w, 0.f));
  ((ushort4*)P_lo)[i] = o;
}

extern "C" void kernel_launch(void* const* d_in, const int* in_sizes, int n_in,
                              void* d_out, int out_size, void* d_ws, size_t ws_size,
                              hipStream_t stream) {
  const float* x  = (const float*)d_in[0];
  const float* gW = (const float*)d_in[1];
  const float* gb = (const float*)d_in[2];
  const float* w1 = (const float*)d_in[3];
  const float* b1 = (const float*)d_in[4];
  const float* w2 = (const float*)d_in[5];
  const float* b2 = (const float*)d_in[6];
  float* y  = (float*)d_out;
  float* gp = (float*)d_out + (size_t)NTOK * DIM;

  // ws layout (bytes) — peak ~48.25 MB (well inside validated envelope):
  //  region0 [0,16M):  A_pack (gemm1 A) -> dead after gemm1 -> w2_bf
  //  region1 [16,32M): w1_bf            -> dead after gemm1
  //  region2 [32,48M): P_lo (bf16 partial) -> h in-place after reduce1
  //  P_hi: parked in d_out's y region (exactly NPAIR*DIM*2 = NTOK*DIM*4 bytes; gp
  //        untouched). reduce1 consumes it BEFORE y is memset for gemm2 atomics.
  //  [48M,..): cnt|done|base|sched|sched_n|bucket (~132 KB) |pairw|tops
  char* ws = (char*)d_ws;
  unsigned short* A_pack = (unsigned short*)(ws);
  unsigned short* w2_bf  = (unsigned short*)(ws);                      // alias, post-gemm1
  unsigned short* w1_bf  = (unsigned short*)(ws + (size_t)(16u << 20));
  unsigned short* P_lo   = (unsigned short*)(ws + (size_t)(32u << 20));
  unsigned short* h_pack = P_lo;                                       // in-place
  unsigned short* P_hi   = (unsigned short*)y;                         // scratch in d_out
  char* tail = ws + (size_t)(48u << 20);
  int*   cnt     = (int*)(tail);                   // 8
  int*   done    = cnt + NE;                       // 1
  int*   base    = done + 1;                       // 9
  int*   sched   = base + NE + 1;                  // <=128
  int*   sched_n = sched + 128;                    // 1
  int*   bucket  = sched_n + 1;                    // NE*NTOK
  float* pairw   = (float*)(bucket + NE * NTOK);   // NPAIR
  int2*  tops    = (int2*)(pairw + NPAIR);         // NTOK

  gate_kernel<<<NTOK / 4, 256, 0, stream>>>(x, gW, gb, gp, tops, pairw, cnt, done);
  bin_sched_kernel<<<NTOK / 256, 256, 0, stream>>>(tops, cnt, bucket, done,
                                                   base, sched, sched_n);
  gather_cvt_kernel<<<NPAIR, 256, 0, stream>>>(x, bucket, base, A_pack,
                                               (const float4*)w1, (ushort4*)w1_bf);
  ffn_gemm<0><<<1152, 256, 0, stream>>>(A_pack, w1_bf, b1, base, sched, sched_n,
                                        bucket, pairw, P_lo, P_hi, y);
  reduce1_kernel<<<NPAIR * DIM / 1024, 256, 0, stream>>>(P_lo, P_hi, b1, base);
  cvt_kernel<<<(NE * DIM * DIM / 4) / 256, 256, 0, stream>>>(
      (const float4*)w2, (ushort4*)w2_bf);
  hipMemsetAsync(y, 0, (size_t)NTOK * DIM * sizeof(float), stream);
  ffn_gemm<1><<<1152, 256, 0, stream>>>(h_pack, w2_bf, b2, base, sched, sched_n,
                                        bucket, pairw, nullptr, nullptr, y);
}